// Round 3
// baseline (777.142 us; speedup 1.0000x reference)
//
#include <hip/hip_runtime.h>
#include <hip/hip_bf16.h>
#include <stdint.h>

#define NNODES  40000
#define NEDGES  800000
#define NE2     (NEDGES/2)
#define NTILES  (NEDGES/16)
#define HBITS   21
#define HSIZE   (1u << HBITS)
#define HMASK   (HSIZE - 1u)
#define EMPTYKEY 0xFFFFFFFFu

typedef __attribute__((ext_vector_type(8))) short short8;   // bf16x8 (4 VGPRs)
typedef __attribute__((ext_vector_type(4))) float f32x4;

__device__ __forceinline__ unsigned hash_key(unsigned k) {
  return (k * 2654435761u) >> (32 - HBITS);
}
__device__ __forceinline__ ushort f2bf(float f) {
  union { __hip_bfloat16 h; ushort u; } c; c.h = __float2bfloat16(f); return c.u;
}
__device__ __forceinline__ float bf2f(ushort u) {
  return __uint_as_float((unsigned)u << 16);
}
__device__ __forceinline__ short8 cvt8(const float* __restrict__ p) {
  f32x4 a = *(const f32x4*)p;
  f32x4 b = *(const f32x4*)(p + 4);
  short8 r;
  r[0] = (short)f2bf(a[0]); r[1] = (short)f2bf(a[1]);
  r[2] = (short)f2bf(a[2]); r[3] = (short)f2bf(a[3]);
  r[4] = (short)f2bf(b[0]); r[5] = (short)f2bf(b[1]);
  r[6] = (short)f2bf(b[2]); r[7] = (short)f2bf(b[3]);
  return r;
}

// ---- CSR build ----
extern "C" __global__ __launch_bounds__(256) void k_hist(
    const int* __restrict__ tgt, int* __restrict__ deg)
{
  int e = blockIdx.x * blockDim.x + threadIdx.x;
  if (e < NEDGES) atomicAdd(&deg[tgt[e]], 1);
}

// single block, 1024 threads: exclusive scan deg[40000] -> off[40001], cur[40000]
extern "C" __global__ __launch_bounds__(1024) void k_scan(
    const int* __restrict__ deg, int* __restrict__ off, int* __restrict__ cur)
{
  __shared__ int part[1024];
  const int t = threadIdx.x;
  const int CH = 40;                      // 1024*40 >= 40000
  const int lo = t * CH, hi = min(lo + CH, NNODES);
  int s = 0;
  for (int i = lo; i < hi; ++i) s += deg[i];
  part[t] = s;
  __syncthreads();
  // Hillis-Steele inclusive scan
  for (int d = 1; d < 1024; d <<= 1) {
    int v = (t >= d) ? part[t - d] : 0;
    __syncthreads();
    part[t] += v;
    __syncthreads();
  }
  int base = (t == 0) ? 0 : part[t - 1];
  int run = base;
  for (int i = lo; i < hi; ++i) {
    off[i] = run; cur[i] = run;
    run += deg[i];
  }
  if (t == 1023) off[NNODES] = part[1023];
}

extern "C" __global__ __launch_bounds__(256) void k_scatter(
    const int* __restrict__ tgt, int* __restrict__ cur, int* __restrict__ eid)
{
  int e = blockIdx.x * blockDim.x + threadIdx.x;
  if (e < NEDGES) {
    int p = atomicAdd(&cur[tgt[e]], 1);
    eid[p] = e;
  }
}

// ---- Kernel 1: msg = relu(eh @ Wm^T + bm), bf16 store; hash insert (+slotof) ----
extern "C" __global__ __launch_bounds__(256) void k_msg(
    const float* __restrict__ eh, const int* __restrict__ src,
    const int* __restrict__ tgt, const float* __restrict__ Wm,
    const float* __restrict__ bm, ushort* __restrict__ msg,
    unsigned* __restrict__ hkeys, int* __restrict__ heads,
    int* __restrict__ nxt, int* __restrict__ slotof)
{
  const int lane = threadIdx.x & 63;
  const int wid  = (int)((blockIdx.x * blockDim.x + threadIdx.x) >> 6);
  const int nw   = (int)((gridDim.x * blockDim.x) >> 6);
  const int m = lane & 15, oct = lane >> 4;

  short8 Bf[2][4];
#pragma unroll
  for (int kk = 0; kk < 2; ++kk)
#pragma unroll
    for (int nf = 0; nf < 4; ++nf)
      Bf[kk][nf] = cvt8(Wm + (size_t)(nf * 16 + m) * 64 + kk * 32 + oct * 8);
  float bias[4];
#pragma unroll
  for (int nf = 0; nf < 4; ++nf) bias[nf] = bm[nf * 16 + m];

  for (int t = wid; t < NTILES; t += nw) {
    const int e0 = t * 16;
    const float* ep = eh + (size_t)(e0 + m) * 64;
    short8 A0 = cvt8(ep + oct * 8);
    short8 A1 = cvt8(ep + 32 + oct * 8);
    f32x4 acc[4] = {};
#pragma unroll
    for (int nf = 0; nf < 4; ++nf) {
      acc[nf] = __builtin_amdgcn_mfma_f32_16x16x32_bf16(A0, Bf[0][nf], acc[nf], 0, 0, 0);
      acc[nf] = __builtin_amdgcn_mfma_f32_16x16x32_bf16(A1, Bf[1][nf], acc[nf], 0, 0, 0);
    }
#pragma unroll
    for (int nf = 0; nf < 4; ++nf) {
#pragma unroll
      for (int r = 0; r < 4; ++r) {
        float v = acc[nf][r] + bias[nf];
        v = v > 0.f ? v : 0.f;
        msg[(size_t)(e0 + oct * 4 + r) * 64 + nf * 16 + m] = f2bf(v);
      }
    }
    if (lane < 16) {
      const int e = e0 + lane;
      const unsigned key = (unsigned)src[e] * (unsigned)NNODES + (unsigned)tgt[e];
      unsigned h = hash_key(key);
      while (true) {
        unsigned prev = atomicCAS(&hkeys[h], EMPTYKEY, key);
        if (prev == EMPTYKEY || prev == key) break;
        h = (h + 1) & HMASK;
      }
      slotof[e] = (int)h;
      nxt[e] = atomicExch(&heads[h], e);
    }
  }
}

// ---- k_agg: agg[n] = sum of msg rows of incoming edges (CSR gather) ----
extern "C" __global__ __launch_bounds__(256) void k_agg(
    const ushort* __restrict__ msg, const int* __restrict__ off,
    const int* __restrict__ eid, float* __restrict__ agg)
{
  const int lane = threadIdx.x & 63;
  const int n = (int)((blockIdx.x * blockDim.x + threadIdx.x) >> 6);
  if (n >= NNODES) return;
  const int beg = off[n], end = off[n + 1];
  float a = 0.f;
  int f = beg;
  for (; f + 4 <= end; f += 4) {
    int e0 = eid[f], e1 = eid[f + 1], e2 = eid[f + 2], e3 = eid[f + 3];
    float v0 = bf2f(msg[(size_t)e0 * 64 + lane]);
    float v1 = bf2f(msg[(size_t)e1 * 64 + lane]);
    float v2 = bf2f(msg[(size_t)e2 * 64 + lane]);
    float v3 = bf2f(msg[(size_t)e3 * 64 + lane]);
    a += (v0 + v1) + (v2 + v3);
  }
  for (; f < end; ++f)
    a += bf2f(msg[(size_t)eid[f] * 64 + lane]);
  agg[(size_t)n * 64 + lane] = a;
}

// ---- Kernel 2: out = relu([x[src]|em|ea](perm) @ Wu^T(perm) + bu) ----
// excl via slotof[rev(e)] (sequential) -> heads -> chain (no hash probe).
extern "C" __global__ __launch_bounds__(256) void k_out(
    const float* __restrict__ x, const float* __restrict__ ea,
    const float* __restrict__ Wu, const float* __restrict__ bu,
    const int* __restrict__ src, const ushort* __restrict__ msg,
    const float* __restrict__ agg, const int* __restrict__ heads,
    const int* __restrict__ nxt, const int* __restrict__ slotof,
    float* __restrict__ out)
{
  const int lane = threadIdx.x & 63;
  const int wid  = (int)((blockIdx.x * blockDim.x + threadIdx.x) >> 6);
  const int nw   = (int)((gridDim.x * blockDim.x) >> 6);
  const int m = lane & 15, oct = lane >> 4;

  const short8 zero8 = {0, 0, 0, 0, 0, 0, 0, 0};
  short8 Bf[5][4];
#pragma unroll
  for (int kk = 0; kk < 5; ++kk) {
    const int k = kk * 32 + oct * 8;
    const int col = (k < 64) ? k : (k < 128 ? k + 16 : k - 64);
#pragma unroll
    for (int nf = 0; nf < 4; ++nf) {
      if (k >= 144) Bf[kk][nf] = zero8;
      else          Bf[kk][nf] = cvt8(Wu + (size_t)(nf * 16 + m) * 144 + col);
    }
  }
  float bias[4];
#pragma unroll
  for (int nf = 0; nf < 4; ++nf) bias[nf] = bu[nf * 16 + m];

  for (int t = wid; t < NTILES; t += nw) {
    const int e0 = t * 16;
    const int eA = e0 + m;
    const int s = src[eA];
    const int rev = (e0 < NE2) ? (eA + NE2) : (eA - NE2);

    // exclusion: chain of key(rev(e)) == (tgt_e, src_e)
    float ex[16];
#pragma unroll
    for (int i = 0; i < 16; ++i) ex[i] = 0.f;
    {
      const int slot = slotof[rev];
      for (int f = heads[slot]; f >= 0; f = nxt[f]) {
        const ushort* mp = msg + (size_t)f * 64;
        short8 w0 = *(const short8*)(mp + oct * 8);
        short8 w1 = *(const short8*)(mp + 32 + oct * 8);
#pragma unroll
        for (int i = 0; i < 8; ++i) {
          ex[i]     += bf2f((ushort)w0[i]);
          ex[8 + i] += bf2f((ushort)w1[i]);
        }
      }
    }

    const float* xp = x + (size_t)s * 64;
    short8 A0 = cvt8(xp + oct * 8);
    short8 A1 = cvt8(xp + 32 + oct * 8);

    const float* ap = agg + (size_t)s * 64;
    f32x4 g0 = *(const f32x4*)(ap + oct * 8);
    f32x4 g1 = *(const f32x4*)(ap + oct * 8 + 4);
    f32x4 g2 = *(const f32x4*)(ap + 32 + oct * 8);
    f32x4 g3 = *(const f32x4*)(ap + 32 + oct * 8 + 4);
    short8 A2, A3;
#pragma unroll
    for (int i = 0; i < 4; ++i) {
      A2[i]     = (short)f2bf(g0[i] - ex[i]);
      A2[4 + i] = (short)f2bf(g1[i] - ex[4 + i]);
      A3[i]     = (short)f2bf(g2[i] - ex[8 + i]);
      A3[4 + i] = (short)f2bf(g3[i] - ex[12 + i]);
    }
    short8 A4 = zero8;
    if (oct < 2) A4 = cvt8(ea + (size_t)eA * 16 + oct * 8);

    f32x4 acc[4] = {};
#pragma unroll
    for (int nf = 0; nf < 4; ++nf) {
      acc[nf] = __builtin_amdgcn_mfma_f32_16x16x32_bf16(A0, Bf[0][nf], acc[nf], 0, 0, 0);
      acc[nf] = __builtin_amdgcn_mfma_f32_16x16x32_bf16(A1, Bf[1][nf], acc[nf], 0, 0, 0);
      acc[nf] = __builtin_amdgcn_mfma_f32_16x16x32_bf16(A2, Bf[2][nf], acc[nf], 0, 0, 0);
      acc[nf] = __builtin_amdgcn_mfma_f32_16x16x32_bf16(A3, Bf[3][nf], acc[nf], 0, 0, 0);
      acc[nf] = __builtin_amdgcn_mfma_f32_16x16x32_bf16(A4, Bf[4][nf], acc[nf], 0, 0, 0);
    }
#pragma unroll
    for (int nf = 0; nf < 4; ++nf) {
#pragma unroll
      for (int r = 0; r < 4; ++r) {
        float v = acc[nf][r] + bias[nf];
        out[(size_t)(e0 + oct * 4 + r) * 64 + nf * 16 + m] = v > 0.f ? v : 0.f;
      }
    }
  }
}

extern "C" void kernel_launch(void* const* d_in, const int* in_sizes, int n_in,
                              void* d_out, int out_size, void* d_ws, size_t ws_size,
                              hipStream_t stream)
{
  const float* x  = (const float*)d_in[0];
  const float* ea = (const float*)d_in[1];
  const float* eh = (const float*)d_in[2];
  const float* Wm = (const float*)d_in[3];
  const float* bm = (const float*)d_in[4];
  const float* Wu = (const float*)d_in[5];
  const float* bu = (const float*)d_in[6];
  const int*   ei = (const int*)d_in[7];
  const int* src = ei;
  const int* tgt = ei + NEDGES;
  float* out = (float*)d_out;

  // workspace layout:
  //   msg    : E*64 bf16 = 102,400,000 @ 0
  //   agg    : N*64 f32  =  10,240,000 @ 102,400,000
  //   hkeys  : HSIZE u32 =   8,388,608 @ 112,640,000
  //   heads  : HSIZE i32 =   8,388,608 @ 121,028,608
  //   nxt    : E i32     =   3,200,000 @ 129,417,216
  //   slotof : E i32     =   3,200,000 @ 132,617,216
  //   deg    : N i32     =     160,000 @ 135,817,216
  //   off    : (N+1) i32 =     160,004 @ 135,977,472
  //   cur    : N i32     =     160,000 @ 136,137,728
  //   eid    : E i32     =   3,200,000 @ 136,297,984   (total ~139.5 MB)
  char* ws = (char*)d_ws;
  ushort*   msg    = (ushort*)(ws);
  float*    agg    = (float*)(ws + 102400000);
  unsigned* hkeys  = (unsigned*)(ws + 112640000);
  int*      heads  = (int*)(ws + 121028608);
  int*      nxt    = (int*)(ws + 129417216);
  int*      slotof = (int*)(ws + 132617216);
  int*      deg    = (int*)(ws + 135817216);
  int*      off    = (int*)(ws + 135977472);
  int*      cur    = (int*)(ws + 136137728);
  int*      eid    = (int*)(ws + 136297984);

  hipMemsetAsync(hkeys, 0xFF, (size_t)HSIZE * 4 * 2, stream);  // hkeys + heads contiguous
  hipMemsetAsync(deg, 0, (size_t)NNODES * 4, stream);

  dim3 blk(256);
  k_hist<<<dim3((NEDGES + 255) / 256), blk, 0, stream>>>(tgt, deg);
  k_scan<<<dim3(1), dim3(1024), 0, stream>>>(deg, off, cur);
  k_scatter<<<dim3((NEDGES + 255) / 256), blk, 0, stream>>>(tgt, cur, eid);
  k_msg<<<dim3(2048), blk, 0, stream>>>(eh, src, tgt, Wm, bm, msg, hkeys, heads, nxt, slotof);
  k_agg<<<dim3((NNODES * 64 + 255) / 256), blk, 0, stream>>>(msg, off, eid, agg);
  k_out<<<dim3(2048), blk, 0, stream>>>(x, ea, Wu, bu, src, msg, agg, heads, nxt, slotof, out);
}